// Round 3
// baseline (1575.103 us; speedup 1.0000x reference)
//
#include <hip/hip_runtime.h>
#include <hip/hip_cooperative_groups.h>
#include <hip/hip_bf16.h>
#include <stdint.h>

namespace cg = cooperative_groups;

#define EMBED 128
#define HIDDEN 256
#define NBLK 1024

typedef __bf16 v8bf __attribute__((ext_vector_type(8)));
typedef float v4f __attribute__((ext_vector_type(4)));

__device__ __forceinline__ float bf2f(unsigned short u){
    union { uint32_t i; float f; } v; v.i = ((uint32_t)u) << 16; return v.f;
}
__device__ __forceinline__ unsigned short f2bf(float f){
    __hip_bfloat16 b = __float2bfloat16(f);
    union { __hip_bfloat16 b; unsigned short u; } cv; cv.b = b; return cv.u;
}
__device__ __forceinline__ uint32_t pack2(float a, float b){
    __hip_bfloat162 t = __float22bfloat162_rn(make_float2(a, b));
    union { __hip_bfloat162 v; uint32_t u; } cv; cv.v = t; return cv.u;
}
__device__ __forceinline__ float lo_f(uint32_t u){ union{uint32_t i;float f;}v; v.i=u<<16; return v.f; }
__device__ __forceinline__ float hi_f(uint32_t u){ union{uint32_t i;float f;}v; v.i=u&0xffff0000u; return v.f; }
__device__ __forceinline__ float silu_f(float x){
    return x * __builtin_amdgcn_rcpf(1.0f + __expf(-x));
}

__device__ __forceinline__ float loadf(const void* b, size_t i, int isf32){
    return isf32 ? ((const float*)b)[i] : bf2f(((const unsigned short*)b)[i]);
}
__device__ __forceinline__ void load8f(const void* base, size_t off, int isf32, float o[8]){
    if (isf32){
        const float* p = (const float*)base + off;
        float4 a = *(const float4*)p, b = *(const float4*)(p + 4);
        o[0]=a.x;o[1]=a.y;o[2]=a.z;o[3]=a.w;o[4]=b.x;o[5]=b.y;o[6]=b.z;o[7]=b.w;
    } else {
        uint4 v = *(const uint4*)((const unsigned short*)base + off);
        uint32_t w[4] = {v.x, v.y, v.z, v.w};
        #pragma unroll
        for (int q = 0; q < 4; q++){ o[2*q] = lo_f(w[q]); o[2*q+1] = hi_f(w[q]); }
    }
}
__device__ __forceinline__ int idx_c(const int* ei, int e, int is64){
    return is64 ? ei[2*(size_t)e] : ei[e];
}
__device__ __forceinline__ int idx_n(const int* ei, int e, int E, int is64){
    return is64 ? ei[2*((size_t)E + e)] : ei[(size_t)E + e];
}

// Self-probe: all 64 lanes scan the SAME 128 u16 samples -> wave-uniform,
// identical across all waves/blocks.
__device__ __forceinline__ int probe_isf32(const void* p, int lane){
    const unsigned short* u = (const unsigned short*)p;
    unsigned short a = u[lane], b = u[64 + lane];
    int bad = (((a >> 7) & 0xFF) >= 0x85) | (((b >> 7) & 0xFF) >= 0x85);
    return __any(bad) ? 1 : 0;
}
__device__ __forceinline__ int probe_is64(const int* ei, int lane){
    int nz = (ei[2*lane + 1] != 0) | (ei[2*(64 + lane) + 1] != 0);
    return __any(nz) ? 0 : 1;
}

// ================= shared device phase bodies =================

__device__ __forceinline__ void prepack_one(int t,
    const void* W1, const void* W2, const void* Wt,
    const void* b1, const void* b2, const void* bt,
    unsigned short* W1p, unsigned short* W2p, unsigned short* Wtp, unsigned short* bpk,
    int isf32)
{
    if (t < 32768){            // W1: [128][256], 16 ntiles x 4 k32
        int j = t & 7, lane = (t >> 3) & 63, k32 = (t >> 9) & 3, nt = t >> 11;
        int k = k32 * 32 + (lane >> 4) * 8 + j, n = nt * 16 + (lane & 15);
        W1p[t] = f2bf(loadf(W1, (size_t)k * HIDDEN + n, isf32));
    } else if (t < 65536){     // W2: [256][128], 8 ntiles x 8 k32
        int t2 = t - 32768;
        int j = t2 & 7, lane = (t2 >> 3) & 63, k32 = (t2 >> 9) & 7, nt = t2 >> 12;
        int k = k32 * 32 + (lane >> 4) * 8 + j, n = nt * 16 + (lane & 15);
        W2p[t2] = f2bf(loadf(W2, (size_t)k * EMBED + n, isf32));
    } else if (t < 81920){     // Wt: [128][128], 8 ntiles x 4 k32
        int t3 = t - 65536;
        int j = t3 & 7, lane = (t3 >> 3) & 63, k32 = (t3 >> 9) & 3, nt = t3 >> 11;
        int k = k32 * 32 + (lane >> 4) * 8 + j, n = nt * 16 + (lane & 15);
        Wtp[t3] = f2bf(loadf(Wt, (size_t)k * EMBED + n, isf32));
    } else if (t < 82176){
        int i = t - 81920; bpk[i] = f2bf(loadf(b1, i, isf32));
    } else if (t < 82304){
        int i = t - 82176; bpk[256 + i] = f2bf(loadf(b2, i, isf32));
    } else if (t < 82432){
        int i = t - 82304; bpk[384 + i] = f2bf(loadf(bt, i, isf32));
    }
}

__device__ __forceinline__ void ln_one(int node, int lane,
    const void* x, const void* g, const void* b,
    unsigned short* h, float* agg, int isf32)
{
    *(float2*)(agg + (size_t)node * EMBED + lane * 2) = make_float2(0.f, 0.f);
    float x0, x1;
    if (isf32){
        float2 v = *(const float2*)((const float*)x + (size_t)node * EMBED + lane * 2);
        x0 = v.x; x1 = v.y;
    } else {
        uint32_t u = *(const uint32_t*)((const unsigned short*)x + (size_t)node * EMBED + lane * 2);
        x0 = lo_f(u); x1 = hi_f(u);
    }
    float s = x0 + x1, ss = x0 * x0 + x1 * x1;
    for (int m = 1; m < 64; m <<= 1){ s += __shfl_xor(s, m); ss += __shfl_xor(ss, m); }
    float mean = s * (1.0f / EMBED);
    float var  = ss * (1.0f / EMBED) - mean * mean;
    float rs   = rsqrtf(var + 1e-5f);
    float g0 = loadf(g, lane * 2, isf32), g1 = loadf(g, lane * 2 + 1, isf32);
    float b0 = loadf(b, lane * 2, isf32), b1v = loadf(b, lane * 2 + 1, isf32);
    float y0 = (x0 - mean) * rs * g0 + b0;
    float y1 = (x1 - mean) * rs * g1 + b1v;
    *(uint32_t*)(h + (size_t)node * EMBED + lane * 2) = pack2(y0, y1);
}

__device__ __forceinline__ void edge_tile(
    int ebase, int E,
    const void* __restrict__ ee, const unsigned short* __restrict__ h,
    const int* __restrict__ eid, const int* __restrict__ cs, const int* __restrict__ ns,
    const unsigned short* __restrict__ W1p, const unsigned short* __restrict__ W2p,
    const unsigned short* __restrict__ bpk,
    float* __restrict__ agg, int isf32,
    unsigned short (*sbuf)[136], unsigned short (*tbuf)[136], float* msg,
    int* cbuf, int* nbuf)
{
    int tid = threadIdx.x;
    int wave = tid >> 6, lane = tid & 63;
    int quad = lane >> 4, l16 = lane & 15;
    int colg = l16 * 8;

    // ---- stage silu(edge + h_c + h_n)
    #pragma unroll
    for (int i = 0; i < 4; i++){
        int row = wave * 16 + i * 4 + quad;
        int sp = ebase + row; if (sp >= E) sp = E - 1;
        int e = eid[sp], c = cs[sp], n = ns[sp];
        if (l16 == 0){ cbuf[row] = c; nbuf[row] = n; }
        float fe[8];
        load8f(ee, (size_t)e * EMBED + colg, isf32, fe);
        uint4 vc = *(const uint4*)(h + (size_t)c * EMBED + colg);
        uint4 vn = *(const uint4*)(h + (size_t)n * EMBED + colg);
        uint32_t pc[4] = {vc.x, vc.y, vc.z, vc.w};
        uint32_t pn[4] = {vn.x, vn.y, vn.z, vn.w};
        uint32_t o[4];
        #pragma unroll
        for (int q = 0; q < 4; q++){
            float a0 = fe[2*q]   + lo_f(pc[q]) + lo_f(pn[q]);
            float a1 = fe[2*q+1] + hi_f(pc[q]) + hi_f(pn[q]);
            o[q] = pack2(silu_f(a0), silu_f(a1));
        }
        *(uint4*)&sbuf[row][colg] = make_uint4(o[0], o[1], o[2], o[3]);
    }
    __syncthreads();

    v4f acc2[4][2];
    {
        float bias2[2];
        #pragma unroll
        for (int j = 0; j < 2; j++) bias2[j] = bf2f(bpk[256 + (wave * 2 + j) * 16 + l16]);
        #pragma unroll
        for (int rt = 0; rt < 4; rt++)
            #pragma unroll
            for (int j = 0; j < 2; j++)
                acc2[rt][j] = (v4f){bias2[j], bias2[j], bias2[j], bias2[j]};
    }

    #pragma unroll
    for (int hf = 0; hf < 2; hf++){
        {
            int ntb = hf * 8 + wave * 2;
            v8bf bw[2][4];
            float bias[2];
            #pragma unroll
            for (int j = 0; j < 2; j++){
                bias[j] = bf2f(bpk[(ntb + j) * 16 + l16]);
                #pragma unroll
                for (int k32 = 0; k32 < 4; k32++)
                    bw[j][k32] = *(const v8bf*)(W1p + ((size_t)((ntb + j) * 4 + k32) * 64 + lane) * 8);
            }
            #pragma unroll
            for (int rt = 0; rt < 4; rt++){
                v8bf a[4];
                #pragma unroll
                for (int k32 = 0; k32 < 4; k32++)
                    a[k32] = *(const v8bf*)&sbuf[rt * 16 + l16][k32 * 32 + quad * 8];
                v4f acc[2];
                #pragma unroll
                for (int j = 0; j < 2; j++) acc[j] = (v4f){bias[j], bias[j], bias[j], bias[j]};
                #pragma unroll
                for (int k32 = 0; k32 < 4; k32++)
                    #pragma unroll
                    for (int j = 0; j < 2; j++)
                        acc[j] = __builtin_amdgcn_mfma_f32_16x16x32_bf16(a[k32], bw[j][k32], acc[j], 0, 0, 0);
                #pragma unroll
                for (int j = 0; j < 2; j++)
                    #pragma unroll
                    for (int r = 0; r < 4; r++)
                        tbuf[rt * 16 + quad * 4 + r][(wave * 2 + j) * 16 + l16] = f2bf(silu_f(acc[j][r]));
            }
        }
        __syncthreads();
        {
            v8bf bw2[2][4];
            #pragma unroll
            for (int j = 0; j < 2; j++)
                #pragma unroll
                for (int kk = 0; kk < 4; kk++)
                    bw2[j][kk] = *(const v8bf*)(W2p + ((size_t)((wave * 2 + j) * 8 + hf * 4 + kk) * 64 + lane) * 8);
            #pragma unroll
            for (int rt = 0; rt < 4; rt++){
                v8bf a[4];
                #pragma unroll
                for (int kk = 0; kk < 4; kk++)
                    a[kk] = *(const v8bf*)&tbuf[rt * 16 + l16][kk * 32 + quad * 8];
                #pragma unroll
                for (int kk = 0; kk < 4; kk++)
                    #pragma unroll
                    for (int j = 0; j < 2; j++)
                        acc2[rt][j] = __builtin_amdgcn_mfma_f32_16x16x32_bf16(a[kk], bw2[j][kk], acc2[rt][j], 0, 0, 0);
            }
        }
        __syncthreads();
    }

    // ---- epilogue 1: msg = h_n * theta -> LDS (aliases sbuf/tbuf)
    #pragma unroll
    for (int rt = 0; rt < 4; rt++){
        #pragma unroll
        for (int j = 0; j < 2; j++){
            int col = (wave * 2 + j) * 16 + l16;
            #pragma unroll
            for (int r = 0; r < 4; r++){
                int row = rt * 16 + quad * 4 + r;
                int n = nbuf[row];
                float hn = bf2f(h[(size_t)n * EMBED + col]);
                msg[row * 132 + col] = acc2[rt][j][r] * hn;
            }
        }
    }
    __syncthreads();

    // ---- epilogue 2: run-segmented reduce over sorted centers
    {
        int col  = tid & 127;
        int half = tid >> 7;
        int r0 = half * 32;
        float acc = 0.f;
        int ccur = -1;
        int first = 1;
        for (int row = r0; row < r0 + 32; ++row){
            if (ebase + row >= E) break;
            int c = cbuf[row];
            if (c != ccur){
                if (ccur >= 0){
                    if (first) atomicAdd(&agg[(size_t)ccur * EMBED + col], acc);
                    else       agg[(size_t)ccur * EMBED + col] = acc;  // interior: exclusive
                    first = 0;
                }
                ccur = c; acc = 0.f;
            }
            acc += msg[row * 132 + col];
        }
        if (ccur >= 0)
            atomicAdd(&agg[(size_t)ccur * EMBED + col], acc);
    }
    __syncthreads();   // LDS reusable by caller
}

__device__ __forceinline__ void node_tile(
    int tile, int N,
    const unsigned short* __restrict__ h, const float* __restrict__ agg,
    const unsigned short* __restrict__ Wtp, const unsigned short* __restrict__ bpk,
    void* __restrict__ out, int isf32,
    unsigned short (*ubuf)[16][136])
{
    int tid = threadIdx.x;
    int wave = tid >> 6, lane = tid & 63;
    int quad = lane >> 4, l16 = lane & 15;
    int nbase = (tile * 4 + wave) * 16;
    int colg = l16 * 8;
    #pragma unroll
    for (int i = 0; i < 4; i++){
        int row = i * 4 + quad;
        int node = nbase + row; int nn = node < N ? node : N - 1;
        uint4 vh = *(const uint4*)(h + (size_t)nn * EMBED + colg);
        float4 a0 = *(const float4*)(agg + (size_t)nn * EMBED + colg);
        float4 a1 = *(const float4*)(agg + (size_t)nn * EMBED + colg + 4);
        uint32_t ph[4] = {vh.x, vh.y, vh.z, vh.w};
        float af[8] = {a0.x, a0.y, a0.z, a0.w, a1.x, a1.y, a1.z, a1.w};
        uint32_t o[4];
        #pragma unroll
        for (int q = 0; q < 4; q++){
            float u0 = lo_f(ph[q]) + af[2 * q];
            float u1 = hi_f(ph[q]) + af[2 * q + 1];
            o[q] = pack2(silu_f(u0), silu_f(u1));
        }
        *(uint4*)&ubuf[wave][row][colg] = make_uint4(o[0], o[1], o[2], o[3]);
    }
    __syncthreads();
    for (int nt = 0; nt < 8; nt++){
        int col = nt * 16 + l16;
        float bc = bf2f(bpk[384 + col]);
        v4f acc = {bc, bc, bc, bc};
        #pragma unroll
        for (int k32 = 0; k32 < 4; k32++){
            v8bf a = *(const v8bf*)&ubuf[wave][l16][k32 * 32 + quad * 8];
            v8bf b = *(const v8bf*)(Wtp + ((size_t)(nt * 4 + k32) * 64 + lane) * 8);
            acc = __builtin_amdgcn_mfma_f32_16x16x32_bf16(a, b, acc, 0, 0, 0);
        }
        #pragma unroll
        for (int r = 0; r < 4; r++){
            int node = nbase + quad * 4 + r;
            if (node < N){
                if (isf32) ((float*)out)[(size_t)node * EMBED + col] = acc[r];
                else ((unsigned short*)out)[(size_t)node * EMBED + col] = f2bf(acc[r]);
            }
        }
    }
    __syncthreads();
}

// ================= fused cooperative kernel =================
__global__ __launch_bounds__(256, 4) void fused_kernel(
    const void* __restrict__ ne, const void* __restrict__ ee, const int* __restrict__ eidx,
    const void* __restrict__ g, const void* __restrict__ be,
    const void* __restrict__ W1, const void* __restrict__ b1,
    const void* __restrict__ W2, const void* __restrict__ b2,
    const void* __restrict__ Wt, const void* __restrict__ bt,
    unsigned short* __restrict__ h, float* __restrict__ agg,
    unsigned short* __restrict__ W1p, unsigned short* __restrict__ W2p,
    unsigned short* __restrict__ Wtp, unsigned short* __restrict__ bpk,
    int* __restrict__ cnt, int* __restrict__ cur,
    int* __restrict__ part, int* __restrict__ partex,
    int* __restrict__ eid, int* __restrict__ cs, int* __restrict__ ns,
    void* __restrict__ out, int N, int E)
{
    cg::grid_group grid = cg::this_grid();
    __shared__ __align__(16) unsigned short sraw[64 * 136 * 2];  // 34816 B
    __shared__ int cbuf[64], nbuf[64];

    int tid = threadIdx.x;
    int wave = tid >> 6, lane = tid & 63;
    int bid = blockIdx.x;
    int gt = bid * 256 + tid;
    const int GT = NBLK * 256;

    int isf32_ne = probe_isf32(ne, lane);
    int isf32_ee = probe_isf32(ee, lane);
    int isf32_w  = probe_isf32(W1, lane);
    int is64     = probe_is64(eidx, lane);

    // ---- P0: cnt zero + prepack + LN (+agg zero), all independent
    for (int k = gt; k < N; k += GT) cnt[k] = 0;
    if (gt < 82432) prepack_one(gt, W1, W2, Wt, b1, b2, bt, W1p, W2p, Wtp, bpk, isf32_w);
    for (int node = bid * 4 + wave; node < N; node += NBLK * 4)
        ln_one(node, lane, ne, g, be, h, agg, isf32_ne);
    grid.sync();

    // ---- P1: histogram of centers
    for (int e = gt; e < E; e += GT) atomicAdd(&cnt[idx_c(eidx, e, is64)], 1);
    grid.sync();

    // ---- P2a: block-local exclusive scan (prefixes persist in LDS)
    int chunk = (N + NBLK - 1) / NBLK;      // 49 at N=50000
    int k0 = bid * chunk;
    int* iLDS = (int*)sraw;
    for (int i = tid; i < chunk; i += 256) iLDS[i] = (k0 + i < N) ? cnt[k0 + i] : 0;
    __syncthreads();
    if (tid == 0){
        int s = 0;
        for (int i = 0; i < chunk; i++){ int v = iLDS[i]; iLDS[i] = s; s += v; }
        part[bid] = s;
    }
    __syncthreads();
    grid.sync();

    // ---- P2b: block 0 scans the NBLK partials
    if (bid == 0){
        int b0 = tid * 4;
        int v[4]; int sl = 0;
        #pragma unroll
        for (int i = 0; i < 4; i++){ v[i] = part[b0 + i]; sl += v[i]; }
        int x = sl;
        for (int m = 1; m < 64; m <<= 1){ int y = __shfl_up(x, m); if (lane >= m) x += y; }
        if (lane == 63) cbuf[wave] = x;
        __syncthreads();
        if (tid == 0){ int a = 0; for (int i = 0; i < 4; i++){ int t2 = cbuf[i]; cbuf[i] = a; a += t2; } }
        __syncthreads();
        int excl = x - sl + cbuf[wave];
        #pragma unroll
        for (int i = 0; i < 4; i++){ partex[b0 + i] = excl; excl += v[i]; }
    }
    grid.sync();

    // ---- P2c: write global cursors
    {
        int base = partex[bid];
        for (int i = tid; i < chunk; i += 256){
            int k = k0 + i;
            if (k < N) cur[k] = base + iLDS[i];
        }
    }
    grid.sync();

    // ---- P3: scatter into center-sorted order
    for (int e = gt; e < E; e += GT){
        int c = idx_c(eidx, e, is64), n = idx_n(eidx, e, E, is64);
        int p = atomicAdd(&cur[c], 1);
        eid[p] = e; cs[p] = c; ns[p] = n;
    }
    grid.sync();

    // ---- P4: edge MLP tiles
    {
        unsigned short (*sbuf)[136] = (unsigned short (*)[136])sraw;
        unsigned short (*tbuf)[136] = (unsigned short (*)[136])(sraw + 64 * 136);
        float* msg = (float*)sraw;
        int ntile = (E + 63) >> 6;
        for (int tile = bid; tile < ntile; tile += NBLK)
            edge_tile(tile * 64, E, ee, h, eid, cs, ns, W1p, W2p, bpk, agg, isf32_ee,
                      sbuf, tbuf, msg, cbuf, nbuf);
    }
    grid.sync();

    // ---- P5: node output tiles
    {
        unsigned short (*ubuf)[16][136] = (unsigned short (*)[16][136])sraw;
        int ntile = (N + 63) >> 6;
        for (int tile = bid; tile < ntile; tile += NBLK)
            node_tile(tile, N, h, agg, Wtp, bpk, out, isf32_ne, ubuf);
    }
}

// ================= standalone fallback kernels =================
__global__ __launch_bounds__(256) void prepack_kernel(
    const void* W1, const void* W2, const void* Wt,
    const void* b1, const void* b2, const void* bt,
    unsigned short* W1p, unsigned short* W2p, unsigned short* Wtp, unsigned short* bpk)
{
    int isf32 = probe_isf32(W1, threadIdx.x & 63);
    int t = blockIdx.x * blockDim.x + threadIdx.x;
    if (t < 82432) prepack_one(t, W1, W2, Wt, b1, b2, bt, W1p, W2p, Wtp, bpk, isf32);
}

__global__ __launch_bounds__(256) void hist_kernel(
    const int* __restrict__ eidx, int E, int* __restrict__ cnt)
{
    int is64 = probe_is64(eidx, threadIdx.x & 63);
    int e = blockIdx.x * 256 + threadIdx.x;
    if (e < E) atomicAdd(&cnt[idx_c(eidx, e, is64)], 1);
}

__global__ __launch_bounds__(1024) void scan_kernel(
    const int* __restrict__ cnt, int* __restrict__ cur, int N)
{
    __shared__ int wpart[16];
    int t = threadIdx.x;
    int Cg = (N + 1023) >> 10;
    int base = t * Cg;
    int s = 0;
    for (int i = 0; i < Cg; i++){ int k = base + i; if (k < N) s += cnt[k]; }
    int lane = t & 63, w = t >> 6;
    int x = s;
    for (int m = 1; m < 64; m <<= 1){ int y = __shfl_up(x, m); if (lane >= m) x += y; }
    if (lane == 63) wpart[w] = x;
    __syncthreads();
    if (t < 16){
        int v = wpart[t];
        for (int m = 1; m < 16; m <<= 1){ int y = __shfl_up(v, m); if (t >= m) v += y; }
        wpart[t] = v;
    }
    __syncthreads();
    int excl = x - s + (w ? wpart[w - 1] : 0);
    for (int i = 0; i < Cg; i++){
        int k = base + i;
        if (k < N){ cur[k] = excl; excl += cnt[k]; }
    }
}

__global__ __launch_bounds__(256) void scatter_kernel(
    const int* __restrict__ eidx, int E, int* __restrict__ cur,
    int* __restrict__ eid, int* __restrict__ cs, int* __restrict__ ns)
{
    int is64 = probe_is64(eidx, threadIdx.x & 63);
    int e = blockIdx.x * 256 + threadIdx.x;
    if (e < E){
        int c = idx_c(eidx, e, is64), n = idx_n(eidx, e, E, is64);
        int p = atomicAdd(&cur[c], 1);
        eid[p] = e; cs[p] = c; ns[p] = n;
    }
}

__global__ __launch_bounds__(256) void ln_kernel(
    const void* __restrict__ x, const void* __restrict__ g, const void* __restrict__ b,
    unsigned short* __restrict__ h, float* __restrict__ agg, int N)
{
    int wave = threadIdx.x >> 6, lane = threadIdx.x & 63;
    int isf32 = probe_isf32(x, lane);
    int node = blockIdx.x * 4 + wave;
    if (node < N) ln_one(node, lane, x, g, b, h, agg, isf32);
}

__global__ __launch_bounds__(256, 4) void edge_kernel(
    const void* __restrict__ ee, const unsigned short* __restrict__ h,
    const int* __restrict__ eid, const int* __restrict__ cs, const int* __restrict__ ns,
    int E,
    const unsigned short* __restrict__ W1p, const unsigned short* __restrict__ W2p,
    const unsigned short* __restrict__ bpk,
    float* __restrict__ agg)
{
    __shared__ __align__(16) unsigned short sraw[64 * 136 * 2];
    __shared__ int cbuf[64], nbuf[64];
    int isf32 = probe_isf32(ee, threadIdx.x & 63);
    edge_tile(blockIdx.x * 64, E, ee, h, eid, cs, ns, W1p, W2p, bpk, agg, isf32,
              (unsigned short (*)[136])sraw,
              (unsigned short (*)[136])(sraw + 64 * 136),
              (float*)sraw, cbuf, nbuf);
}

__global__ __launch_bounds__(256) void node_out_kernel(
    const void* __restrict__ ne,
    const unsigned short* __restrict__ h, const float* __restrict__ agg,
    const unsigned short* __restrict__ Wtp, const unsigned short* __restrict__ bpk,
    void* __restrict__ out, int N)
{
    __shared__ __align__(16) unsigned short ubuf[4][16][136];
    int isf32 = probe_isf32(ne, threadIdx.x & 63);
    node_tile(blockIdx.x, N, h, agg, Wtp, bpk, out, isf32, ubuf);
}

extern "C" void kernel_launch(void* const* d_in, const int* in_sizes, int n_in,
                              void* d_out, int out_size, void* d_ws, size_t ws_size,
                              hipStream_t stream)
{
    const void* ne = d_in[0];
    const void* ee = d_in[1];
    const int* eidx = (const int*)d_in[2];
    const void* g  = d_in[3];
    const void* be = d_in[4];
    const void* W1 = d_in[5];
    const void* b1 = d_in[6];
    const void* W2 = d_in[7];
    const void* b2 = d_in[8];
    const void* Wt = d_in[9];
    const void* bt = d_in[10];
    int N = in_sizes[0] / EMBED;   // 50000
    int E = in_sizes[2] / 2;       // 640000

    char* ws = (char*)d_ws;
    size_t off = 0;
    unsigned short* h = (unsigned short*)(ws + off); off += (size_t)N * EMBED * 2;
    off = (off + 255) & ~(size_t)255;
    float* agg = (float*)(ws + off);                 off += (size_t)N * EMBED * 4;
    off = (off + 255) & ~(size_t)255;
    unsigned short* W1p = (unsigned short*)(ws + off); off += 32768 * 2;
    unsigned short* W2p = (unsigned short*)(ws + off); off += 32768 * 2;
    unsigned short* Wtp = (unsigned short*)(ws + off); off += 16384 * 2;
    unsigned short* bpk = (unsigned short*)(ws + off); off += 512 * 2;
    off = (off + 255) & ~(size_t)255;
    int* cnt = (int*)(ws + off); off += (size_t)N * 4;
    off = (off + 255) & ~(size_t)255;
    int* cur = (int*)(ws + off); off += (size_t)N * 4;
    off = (off + 255) & ~(size_t)255;
    int* part   = (int*)(ws + off); off += (size_t)NBLK * 4;
    int* partex = (int*)(ws + off); off += (size_t)NBLK * 4;
    off = (off + 255) & ~(size_t)255;
    int* eid = (int*)(ws + off); off += (size_t)E * 4;
    int* cs  = (int*)(ws + off); off += (size_t)E * 4;
    int* ns  = (int*)(ws + off); off += (size_t)E * 4;

    void* kargs[] = { (void*)&ne, (void*)&ee, (void*)&eidx, (void*)&g, (void*)&be,
                      (void*)&W1, (void*)&b1, (void*)&W2, (void*)&b2, (void*)&Wt, (void*)&bt,
                      (void*)&h, (void*)&agg, (void*)&W1p, (void*)&W2p, (void*)&Wtp, (void*)&bpk,
                      (void*)&cnt, (void*)&cur, (void*)&part, (void*)&partex,
                      (void*)&eid, (void*)&cs, (void*)&ns, (void*)&d_out, (void*)&N, (void*)&E };
    hipError_t err = hipLaunchCooperativeKernel((const void*)fused_kernel,
                                                dim3(NBLK), dim3(256), kargs, 0, stream);
    if (err != hipSuccess){
        (void)hipGetLastError();   // clear sticky error, use multi-launch fallback
        hipMemsetAsync(cnt, 0, (size_t)N * 4, stream);
        prepack_kernel<<<(82432 + 255) / 256, 256, 0, stream>>>(W1, W2, Wt, b1, b2, bt,
                                                                W1p, W2p, Wtp, bpk);
        hist_kernel<<<(E + 255) / 256, 256, 0, stream>>>(eidx, E, cnt);
        scan_kernel<<<1, 1024, 0, stream>>>(cnt, cur, N);
        scatter_kernel<<<(E + 255) / 256, 256, 0, stream>>>(eidx, E, cur, eid, cs, ns);
        ln_kernel<<<(N + 3) / 4, 256, 0, stream>>>(ne, g, be, h, agg, N);
        edge_kernel<<<(E + 63) / 64, 256, 0, stream>>>(ee, h, eid, cs, ns, E,
                                                       W1p, W2p, bpk, agg);
        node_out_kernel<<<(N + 63) / 64, 256, 0, stream>>>(ne, h, agg, Wtp, bpk,
                                                           d_out, N);
    }
}

// Round 5
// 737.335 us; speedup vs baseline: 2.1362x; 2.1362x over previous
//
#include <hip/hip_runtime.h>
#include <hip/hip_bf16.h>
#include <stdint.h>

#define EMBED 128
#define HIDDEN 256

typedef __bf16 v8bf __attribute__((ext_vector_type(8)));
typedef float v4f __attribute__((ext_vector_type(4)));

__device__ __forceinline__ float bf2f(unsigned short u){
    union { uint32_t i; float f; } v; v.i = ((uint32_t)u) << 16; return v.f;
}
__device__ __forceinline__ unsigned short f2bf(float f){
    __hip_bfloat16 b = __float2bfloat16(f);
    union { __hip_bfloat16 b; unsigned short u; } cv; cv.b = b; return cv.u;
}
__device__ __forceinline__ uint32_t pack2(float a, float b){
    __hip_bfloat162 t = __float22bfloat162_rn(make_float2(a, b));
    union { __hip_bfloat162 v; uint32_t u; } cv; cv.v = t; return cv.u;
}
__device__ __forceinline__ float lo_f(uint32_t u){ union{uint32_t i;float f;}v; v.i=u<<16; return v.f; }
__device__ __forceinline__ float hi_f(uint32_t u){ union{uint32_t i;float f;}v; v.i=u&0xffff0000u; return v.f; }
__device__ __forceinline__ float silu_f(float x){
    return x * __builtin_amdgcn_rcpf(1.0f + __expf(-x));
}

__device__ __forceinline__ float loadf(const void* b, size_t i, int isf32){
    return isf32 ? ((const float*)b)[i] : bf2f(((const unsigned short*)b)[i]);
}
__device__ __forceinline__ void load8f(const void* base, size_t off, int isf32, float o[8]){
    if (isf32){
        const float* p = (const float*)base + off;
        float4 a = *(const float4*)p, b = *(const float4*)(p + 4);
        o[0]=a.x;o[1]=a.y;o[2]=a.z;o[3]=a.w;o[4]=b.x;o[5]=b.y;o[6]=b.z;o[7]=b.w;
    } else {
        uint4 v = *(const uint4*)((const unsigned short*)base + off);
        uint32_t w[4] = {v.x, v.y, v.z, v.w};
        #pragma unroll
        for (int q = 0; q < 4; q++){ o[2*q] = lo_f(w[q]); o[2*q+1] = hi_f(w[q]); }
    }
}
__device__ __forceinline__ int idx_c(const int* ei, int e, int is64){
    return is64 ? ei[2*(size_t)e] : ei[e];
}
__device__ __forceinline__ int idx_n(const int* ei, int e, int E, int is64){
    return is64 ? ei[2*((size_t)E + e)] : ei[(size_t)E + e];
}

// Self-probe: all 64 lanes scan the SAME 128 u16 samples -> wave-uniform,
// identical across all waves/blocks.
__device__ __forceinline__ int probe_isf32(const void* p, int lane){
    const unsigned short* u = (const unsigned short*)p;
    unsigned short a = u[lane], b = u[64 + lane];
    int bad = (((a >> 7) & 0xFF) >= 0x85) | (((b >> 7) & 0xFF) >= 0x85);
    return __any(bad) ? 1 : 0;
}
__device__ __forceinline__ int probe_is64(const int* ei, int lane){
    int nz = (ei[2*lane + 1] != 0) | (ei[2*(64 + lane) + 1] != 0);
    return __any(nz) ? 0 : 1;
}

// ---------------- shared phase bodies ----------------
__device__ __forceinline__ void prepack_one(int t,
    const void* W1, const void* W2, const void* Wt,
    const void* b1, const void* b2, const void* bt,
    unsigned short* W1p, unsigned short* W2p, unsigned short* Wtp, unsigned short* bpk,
    int isf32)
{
    if (t < 32768){            // W1: [128][256], 16 ntiles x 4 k32
        int j = t & 7, lane = (t >> 3) & 63, k32 = (t >> 9) & 3, nt = t >> 11;
        int k = k32 * 32 + (lane >> 4) * 8 + j, n = nt * 16 + (lane & 15);
        W1p[t] = f2bf(loadf(W1, (size_t)k * HIDDEN + n, isf32));
    } else if (t < 65536){     // W2: [256][128], 8 ntiles x 8 k32
        int t2 = t - 32768;
        int j = t2 & 7, lane = (t2 >> 3) & 63, k32 = (t2 >> 9) & 7, nt = t2 >> 12;
        int k = k32 * 32 + (lane >> 4) * 8 + j, n = nt * 16 + (lane & 15);
        W2p[t2] = f2bf(loadf(W2, (size_t)k * EMBED + n, isf32));
    } else if (t < 81920){     // Wt: [128][128], 8 ntiles x 4 k32
        int t3 = t - 65536;
        int j = t3 & 7, lane = (t3 >> 3) & 63, k32 = (t3 >> 9) & 3, nt = t3 >> 11;
        int k = k32 * 32 + (lane >> 4) * 8 + j, n = nt * 16 + (lane & 15);
        Wtp[t3] = f2bf(loadf(Wt, (size_t)k * EMBED + n, isf32));
    } else if (t < 82176){
        int i = t - 81920; bpk[i] = f2bf(loadf(b1, i, isf32));
    } else if (t < 82304){
        int i = t - 82176; bpk[256 + i] = f2bf(loadf(b2, i, isf32));
    } else if (t < 82432){
        int i = t - 82304; bpk[384 + i] = f2bf(loadf(bt, i, isf32));
    }
}

__device__ __forceinline__ void ln_one(int node, int lane,
    const void* x, const void* g, const void* b,
    unsigned short* h, float* agg, int isf32)
{
    *(float2*)(agg + (size_t)node * EMBED + lane * 2) = make_float2(0.f, 0.f);
    float x0, x1;
    if (isf32){
        float2 v = *(const float2*)((const float*)x + (size_t)node * EMBED + lane * 2);
        x0 = v.x; x1 = v.y;
    } else {
        uint32_t u = *(const uint32_t*)((const unsigned short*)x + (size_t)node * EMBED + lane * 2);
        x0 = lo_f(u); x1 = hi_f(u);
    }
    float s = x0 + x1, ss = x0 * x0 + x1 * x1;
    for (int m = 1; m < 64; m <<= 1){ s += __shfl_xor(s, m); ss += __shfl_xor(ss, m); }
    float mean = s * (1.0f / EMBED);
    float var  = ss * (1.0f / EMBED) - mean * mean;
    float rs   = rsqrtf(var + 1e-5f);
    float g0 = loadf(g, lane * 2, isf32), g1 = loadf(g, lane * 2 + 1, isf32);
    float b0 = loadf(b, lane * 2, isf32), b1v = loadf(b, lane * 2 + 1, isf32);
    float y0 = (x0 - mean) * rs * g0 + b0;
    float y1 = (x1 - mean) * rs * g1 + b1v;
    *(uint32_t*)(h + (size_t)node * EMBED + lane * 2) = pack2(y0, y1);
}

// ---------------- prep: cnt-zero + prepack + LN(+agg-zero), all independent ----------------
__global__ __launch_bounds__(256) void prep_kernel(
    const void* __restrict__ ne, const void* __restrict__ g, const void* __restrict__ be,
    const void* __restrict__ W1, const void* __restrict__ W2, const void* __restrict__ Wt,
    const void* __restrict__ b1, const void* __restrict__ b2, const void* __restrict__ bt,
    unsigned short* __restrict__ h, float* __restrict__ agg,
    unsigned short* __restrict__ W1p, unsigned short* __restrict__ W2p,
    unsigned short* __restrict__ Wtp, unsigned short* __restrict__ bpk,
    int* __restrict__ cnt, int N)
{
    int tid = threadIdx.x, bid = blockIdx.x;
    int wave = tid >> 6, lane = tid & 63;
    int gt = bid * 256 + tid;
    int GT = gridDim.x * 256;
    int isf32_ne = probe_isf32(ne, lane);
    int isf32_w  = probe_isf32(W1, lane);
    for (int k = gt; k < N; k += GT) cnt[k] = 0;
    if (gt < 82432) prepack_one(gt, W1, W2, Wt, b1, b2, bt, W1p, W2p, Wtp, bpk, isf32_w);
    for (int node = bid * 4 + wave; node < N; node += gridDim.x * 4)
        ln_one(node, lane, ne, g, be, h, agg, isf32_ne);
}

// ---------------- counting sort: hist -> 2-level scan -> scatter(eid only) ----------------
__global__ __launch_bounds__(256) void hist_kernel(
    const int* __restrict__ eidx, int E, int* __restrict__ cnt)
{
    int is64 = probe_is64(eidx, threadIdx.x & 63);
    int e = blockIdx.x * 256 + threadIdx.x;
    if (e < E) atomicAdd(&cnt[idx_c(eidx, e, is64)], 1);
}

// per-256-chunk local exclusive scan; block totals to bsum
__global__ __launch_bounds__(256) void scan_a_kernel(
    const int* __restrict__ cnt, int* __restrict__ cur, int* __restrict__ bsum, int N)
{
    __shared__ int wp[4];
    int t = threadIdx.x, lane = t & 63, w = t >> 6;
    int k = blockIdx.x * 256 + t;
    int v = (k < N) ? cnt[k] : 0;
    int x = v;
    for (int m = 1; m < 64; m <<= 1){ int y = __shfl_up(x, m); if (lane >= m) x += y; }
    if (lane == 63) wp[w] = x;
    __syncthreads();
    if (t == 0){ int a = 0; for (int i = 0; i < 4; i++){ int s = wp[i]; wp[i] = a; a += s; } bsum[blockIdx.x] = a; }
    __syncthreads();
    if (k < N) cur[k] = x - v + wp[w];
}

// single block: exclusive scan of NB (<=256) block sums
__global__ __launch_bounds__(256) void scan_b_kernel(
    const int* __restrict__ bsum, int* __restrict__ bexcl, int NB)
{
    __shared__ int wp[4];
    int t = threadIdx.x, lane = t & 63, w = t >> 6;
    int v = (t < NB) ? bsum[t] : 0;
    int x = v;
    for (int m = 1; m < 64; m <<= 1){ int y = __shfl_up(x, m); if (lane >= m) x += y; }
    if (lane == 63) wp[w] = x;
    __syncthreads();
    if (t == 0){ int a = 0; for (int i = 0; i < 4; i++){ int s = wp[i]; wp[i] = a; a += s; } }
    __syncthreads();
    if (t < NB) bexcl[t] = x - v + wp[w];
}

__global__ __launch_bounds__(256) void scatter_kernel(
    const int* __restrict__ eidx, int E, int* __restrict__ cur,
    const int* __restrict__ bexcl, int* __restrict__ eid)
{
    int is64 = probe_is64(eidx, threadIdx.x & 63);
    int e = blockIdx.x * 256 + threadIdx.x;
    if (e < E){
        int c = idx_c(eidx, e, is64);
        int p = bexcl[c >> 8] + atomicAdd(&cur[c], 1);
        eid[p] = e;
    }
}

// ---------------- Edge MLP on center-sorted edges ----------------
// LDS: sraw (sbuf 17.4K + tbuf 17.4K; msg f32[64][132] aliases both in epilogue)
//      + cbuf/nbuf = 35.3 KB -> 4 blocks/CU.
// hn for the epilogue is PREFETCHED into registers right after staging so its
// random-gather latency hides under the GEMMs.
__global__ __launch_bounds__(256, 4) void edge_kernel(
    const void* __restrict__ ee, const unsigned short* __restrict__ h,
    const int* __restrict__ eid, const int* __restrict__ eidx, int E,
    const unsigned short* __restrict__ W1p, const unsigned short* __restrict__ W2p,
    const unsigned short* __restrict__ bpk,
    float* __restrict__ agg)
{
    __shared__ __align__(16) unsigned short sraw[64 * 136 * 2]; // 34816 B
    __shared__ int cbuf[64], nbuf[64];
    unsigned short (*sbuf)[136] = (unsigned short (*)[136])sraw;
    unsigned short (*tbuf)[136] = (unsigned short (*)[136])(sraw + 64 * 136);
    float* msg = (float*)sraw;   // 64*132*4 = 33792 B <= 34816

    int tid = threadIdx.x;
    int wave = tid >> 6, lane = tid & 63;
    int quad = lane >> 4, l16 = lane & 15;
    int isf32 = probe_isf32(ee, lane);
    int is64  = probe_is64(eidx, lane);
    int ebase = blockIdx.x * 64;
    int colg = l16 * 8;

    // ---- stage silu(edge + h_c + h_n); batch the eid->eidx->h dependency levels
    int e4[4], c4[4], n4[4];
    #pragma unroll
    for (int i = 0; i < 4; i++){
        int sp = ebase + wave * 16 + i * 4 + quad;
        if (sp >= E) sp = E - 1;
        e4[i] = eid[sp];
    }
    #pragma unroll
    for (int i = 0; i < 4; i++){
        c4[i] = idx_c(eidx, e4[i], is64);
        n4[i] = idx_n(eidx, e4[i], E, is64);
    }
    #pragma unroll
    for (int i = 0; i < 4; i++){
        int row = wave * 16 + i * 4 + quad;
        if (l16 == 0){ cbuf[row] = c4[i]; nbuf[row] = n4[i]; }
        float fe[8];
        load8f(ee, (size_t)e4[i] * EMBED + colg, isf32, fe);
        uint4 vc = *(const uint4*)(h + (size_t)c4[i] * EMBED + colg);
        uint4 vn = *(const uint4*)(h + (size_t)n4[i] * EMBED + colg);
        uint32_t pc[4] = {vc.x, vc.y, vc.z, vc.w};
        uint32_t pn[4] = {vn.x, vn.y, vn.z, vn.w};
        uint32_t o[4];
        #pragma unroll
        for (int q = 0; q < 4; q++){
            float a0 = fe[2*q]   + lo_f(pc[q]) + lo_f(pn[q]);
            float a1 = fe[2*q+1] + hi_f(pc[q]) + hi_f(pn[q]);
            o[q] = pack2(silu_f(a0), silu_f(a1));
        }
        *(uint4*)&sbuf[row][colg] = make_uint4(o[0], o[1], o[2], o[3]);
    }
    __syncthreads();

    // ---- prefetch epilogue hn into registers (latency hides under GEMMs)
    unsigned short hn_pre[4][2][4];
    #pragma unroll
    for (int rt = 0; rt < 4; rt++)
        #pragma unroll
        for (int r = 0; r < 4; r++){
            int row = rt * 16 + quad * 4 + r;
            int n = nbuf[row];
            #pragma unroll
            for (int j = 0; j < 2; j++)
                hn_pre[rt][j][r] = h[(size_t)n * EMBED + (wave * 2 + j) * 16 + l16];
        }

    // ---- GEMM2 accumulators persist across both hidden halves
    v4f acc2[4][2];
    {
        float bias2[2];
        #pragma unroll
        for (int j = 0; j < 2; j++) bias2[j] = bf2f(bpk[256 + (wave * 2 + j) * 16 + l16]);
        #pragma unroll
        for (int rt = 0; rt < 4; rt++)
            #pragma unroll
            for (int j = 0; j < 2; j++)
                acc2[rt][j] = (v4f){bias2[j], bias2[j], bias2[j], bias2[j]};
    }

    #pragma unroll
    for (int hf = 0; hf < 2; hf++){
        // ---- GEMM1 half hf: wave computes hidden ntiles {hf*8+2w, hf*8+2w+1}
        {
            int ntb = hf * 8 + wave * 2;
            v8bf bw[2][4];
            float bias[2];
            #pragma unroll
            for (int j = 0; j < 2; j++){
                bias[j] = bf2f(bpk[(ntb + j) * 16 + l16]);
                #pragma unroll
                for (int k32 = 0; k32 < 4; k32++)
                    bw[j][k32] = *(const v8bf*)(W1p + ((size_t)((ntb + j) * 4 + k32) * 64 + lane) * 8);
            }
            #pragma unroll
            for (int rt = 0; rt < 4; rt++){
                v8bf a[4];
                #pragma unroll
                for (int k32 = 0; k32 < 4; k32++)
                    a[k32] = *(const v8bf*)&sbuf[rt * 16 + l16][k32 * 32 + quad * 8];
                v4f acc[2];
                #pragma unroll
                for (int j = 0; j < 2; j++) acc[j] = (v4f){bias[j], bias[j], bias[j], bias[j]};
                #pragma unroll
                for (int k32 = 0; k32 < 4; k32++)
                    #pragma unroll
                    for (int j = 0; j < 2; j++)
                        acc[j] = __builtin_amdgcn_mfma_f32_16x16x32_bf16(a[k32], bw[j][k32], acc[j], 0, 0, 0);
                #pragma unroll
                for (int j = 0; j < 2; j++)
                    #pragma unroll
                    for (int r = 0; r < 4; r++)
                        tbuf[rt * 16 + quad * 4 + r][(wave * 2 + j) * 16 + l16] = f2bf(silu_f(acc[j][r]));
            }
        }
        __syncthreads();
        // ---- GEMM2, K-chunk hf
        {
            v8bf bw2[2][4];
            #pragma unroll
            for (int j = 0; j < 2; j++)
                #pragma unroll
                for (int kk = 0; kk < 4; kk++)
                    bw2[j][kk] = *(const v8bf*)(W2p + ((size_t)((wave * 2 + j) * 8 + hf * 4 + kk) * 64 + lane) * 8);
            #pragma unroll
            for (int rt = 0; rt < 4; rt++){
                v8bf a[4];
                #pragma unroll
                for (int kk = 0; kk < 4; kk++)
                    a[kk] = *(const v8bf*)&tbuf[rt * 16 + l16][kk * 32 + quad * 8];
                #pragma unroll
                for (int kk = 0; kk < 4; kk++)
                    #pragma unroll
                    for (int j = 0; j < 2; j++)
                        acc2[rt][j] = __builtin_amdgcn_mfma_f32_16x16x32_bf16(a[kk], bw2[j][kk], acc2[rt][j], 0, 0, 0);
            }
        }
        __syncthreads();   // hf=0: before GEMM1 half1 overwrites tbuf; hf=1: before msg aliases sraw
    }

    // ---- epilogue 1: msg = h_n * theta -> LDS (aliases sbuf/tbuf, both dead)
    #pragma unroll
    for (int rt = 0; rt < 4; rt++){
        #pragma unroll
        for (int j = 0; j < 2; j++){
            int col = (wave * 2 + j) * 16 + l16;
            #pragma unroll
            for (int r = 0; r < 4; r++){
                int row = rt * 16 + quad * 4 + r;
                msg[row * 132 + col] = acc2[rt][j][r] * bf2f(hn_pre[rt][j][r]);
            }
        }
    }
    __syncthreads();

    // ---- epilogue 2: run-segmented reduce over sorted centers
    {
        int col  = tid & 127;
        int half = tid >> 7;
        int r0 = half * 32;
        float acc = 0.f;
        int ccur = -1;
        int first = 1;
        for (int row = r0; row < r0 + 32; ++row){
            if (ebase + row >= E) break;
            int c = cbuf[row];
            if (c != ccur){
                if (ccur >= 0){
                    if (first) atomicAdd(&agg[(size_t)ccur * EMBED + col], acc);
                    else       agg[(size_t)ccur * EMBED + col] = acc;  // interior: exclusive
                    first = 0;
                }
                ccur = c; acc = 0.f;
            }
            acc += msg[row * 132 + col];
        }
        if (ccur >= 0)
            atomicAdd(&agg[(size_t)ccur * EMBED + col], acc);
    }
}

// ---------------- Node output: out = silu(h + agg) @ Wt + bt ----------------
__global__ __launch_bounds__(256) void node_out_kernel(
    const void* __restrict__ ne,
    const unsigned short* __restrict__ h, const float* __restrict__ agg,
    const unsigned short* __restrict__ Wtp, const unsigned short* __restrict__ bpk,
    void* __restrict__ out, int N)
{
    __shared__ __align__(16) unsigned short ubuf[4][16][136];
    int tid = threadIdx.x;
    int wave = tid >> 6, lane = tid & 63;
    int isf32 = probe_isf32(ne, lane);
    int quad = lane >> 4, l16 = lane & 15;
    int nbase = (blockIdx.x * 4 + wave) * 16;
    int colg = l16 * 8;
    #pragma unroll
    for (int i = 0; i < 4; i++){
        int row = i * 4 + quad;
        int node = nbase + row; int nn = node < N ? node : N - 1;
        uint4 vh = *(const uint4*)(h + (size_t)nn * EMBED + colg);
        float4 a0 = *(const float4*)(agg + (size_t)nn * EMBED + colg);
        float4 a1 = *(const float4*)(agg + (size_t)nn * EMBED + colg + 4);
        uint32_t ph[4] = {vh.x, vh.y, vh.z, vh.w};
        float af[8] = {a0.x, a0.y, a0.z, a0.w, a1.x, a1.y, a1.z, a1.w};
        uint32_t o[4];
        #pragma unroll
        for (int q = 0; q < 4; q++){
            float u0 = lo_f(ph[q]) + af[2 * q];
            float u1 = hi_f(ph[q]) + af[2 * q + 1];
            o[q] = pack2(silu_f(u0), silu_f(u1));
        }
        *(uint4*)&ubuf[wave][row][colg] = make_uint4(o[0], o[1], o[2], o[3]);
    }
    __syncthreads();
    for (int nt = 0; nt < 8; nt++){
        int col = nt * 16 + l16;
        float bc = bf2f(bpk[384 + col]);
        v4f acc = {bc, bc, bc, bc};
        #pragma unroll
        for (int k32 = 0; k32 < 4; k32++){
            v8bf a = *(const v8bf*)&ubuf[wave][l16][k32 * 32 + quad * 8];
            v8bf b = *(const v8bf*)(Wtp + ((size_t)(nt * 4 + k32) * 64 + lane) * 8);
            acc = __builtin_amdgcn_mfma_f32_16x16x32_bf16(a, b, acc, 0, 0, 0);
        }
        #pragma unroll
        for (int r = 0; r < 4; r++){
            int node = nbase + quad * 4 + r;
            if (node < N){
                if (isf32) ((float*)out)[(size_t)node * EMBED + col] = acc[r];
                else ((unsigned short*)out)[(size_t)node * EMBED + col] = f2bf(acc[r]);
            }
        }
    }
}

extern "C" void kernel_launch(void* const* d_in, const int* in_sizes, int n_in,
                              void* d_out, int out_size, void* d_ws, size_t ws_size,
                              hipStream_t stream)
{
    const void* ne = d_in[0];
    const void* ee = d_in[1];
    const int* eidx = (const int*)d_in[2];
    const void* g  = d_in[3];
    const void* be = d_in[4];
    const void* W1 = d_in[5];
    const void* b1 = d_in[6];
    const void* W2 = d_in[7];
    const void* b2 = d_in[8];
    const void* Wt = d_in[9];
    const void* bt = d_in[10];
    int N = in_sizes[0] / EMBED;   // 50000
    int E = in_sizes[2] / 2;       // 640000

    char* ws = (char*)d_ws;
    size_t off = 0;
    unsigned short* h = (unsigned short*)(ws + off); off += (size_t)N * EMBED * 2;
    off = (off + 255) & ~(size_t)255;
    float* agg = (float*)(ws + off);                 off += (size_t)N * EMBED * 4;
    off = (off + 255) & ~(size_t)255;
    unsigned short* W1p = (unsigned short*)(ws + off); off += 32768 * 2;
    unsigned short* W2p = (unsigned short*)(ws + off); off += 32768 * 2;
    unsigned short* Wtp = (unsigned short*)(ws + off); off += 16384 * 2;
    unsigned short* bpk = (unsigned short*)(ws + off); off += 512 * 2;
    off = (off + 255) & ~(size_t)255;
    int* cnt = (int*)(ws + off); off += (size_t)N * 4;
    off = (off + 255) & ~(size_t)255;
    int* cur = (int*)(ws + off); off += (size_t)N * 4;
    off = (off + 255) & ~(size_t)255;
    int* bsum  = (int*)(ws + off); off += 1024;
    int* bexcl = (int*)(ws + off); off += 1024;
    off = (off + 255) & ~(size_t)255;
    int* eid = (int*)(ws + off); off += (size_t)E * 4;

    int NB = (N + 255) / 256;   // 196 at N=50000 (must be <= 256)

    prep_kernel<<<2048, 256, 0, stream>>>(ne, g, be, W1, W2, Wt, b1, b2, bt,
                                          h, agg, W1p, W2p, Wtp, bpk, cnt, N);
    hist_kernel<<<(E + 255) / 256, 256, 0, stream>>>(eidx, E, cnt);
    scan_a_kernel<<<NB, 256, 0, stream>>>(cnt, cur, bsum, N);
    scan_b_kernel<<<1, 256, 0, stream>>>(bsum, bexcl, NB);
    scatter_kernel<<<(E + 255) / 256, 256, 0, stream>>>(eidx, E, cur, bexcl, eid);
    edge_kernel<<<(E + 63) / 64, 256, 0, stream>>>(ee, h, eid, eidx, E,
                                                   W1p, W2p, bpk, agg);
    node_out_kernel<<<(N + 63) / 64, 256, 0, stream>>>(ne, h, agg, Wtp, bpk,
                                                       d_out, N);
}